// Round 12
// baseline (486.925 us; speedup 1.0000x reference)
//
#include <hip/hip_runtime.h>
#include <hip/hip_bf16.h>

#define BATCH   512
#define INDIM   768
#define HID     256
#define NGEN    4095
#define NOBS    15
#define OUTDIM  512
#define DIM     64

typedef __hip_bfloat16 bf16;

// static device scratch: no reliance on ws_size
__device__ int   g_isf32;
__device__ float g_theta[(size_t)BATCH*NGEN];
__device__ float g_q[BATCH*NOBS];

__device__ __forceinline__ float tof(bf16 v){ return __bfloat162float(v); }
__device__ __forceinline__ float silu(float x){ return x / (1.f + __expf(-x)); }

template<bool F32>
__device__ __forceinline__ float LD(const void* p, size_t i){
  if(F32) return ((const float*)p)[i];
  else    return tof(((const bf16*)p)[i]);
}

// put bit p of x at bit 2p (6-bit input)
__device__ __forceinline__ unsigned spread6(unsigned x){
  return (x&1u) | ((x&2u)<<1) | ((x&4u)<<2) | ((x&8u)<<3) | ((x&16u)<<4) | ((x&32u)<<5);
}

__constant__ int c_WA[15] = {0,0,0,0,0,1,1,1,1,2,2,2,3,3,4};
__constant__ int c_WB[15] = {1,2,3,4,5,2,3,4,5,3,4,5,4,5,5};
__constant__ int c_Lt[6]  = {1,2,2,3,3,3};
__constant__ int c_Kt[6]  = {0,0,1,0,1,2};

// ---- dtype sniffer (UNCHANGED; stays the FIRST kernel) ----
__global__ __launch_bounds__(256) void k_detect(const unsigned* __restrict__ w1raw){
  __shared__ int sh[256];
  const int t = threadIdx.x;
  int c = 0;
  for(int i=t;i<1024;i+=256){
    unsigned ub = (w1raw[i]>>8) & 0x7Fu;
    if(ub>=0x30u && ub<=0x3Fu) c++;
  }
  sh[t] = c;
  __syncthreads();
  for(int s=128;s>0;s>>=1){
    if(t<s) sh[t] += sh[t+s];
    __syncthreads();
  }
  if(t==0) g_isf32 = (sh[0] < 512) ? 1 : 0;
}

// ---------------- enc MLP (UNCHANGED R10 body) ----------------
template<bool F32>
__device__ void enc_body(const void* __restrict__ x, const void* __restrict__ W1,
                         const void* __restrict__ b1, const void* __restrict__ W2,
                         const void* __restrict__ b2,
                         float (*xl_t)[8], float (*hl_t)[8]){
  const int t  = threadIdx.x;
  const int b0 = (blockIdx.x >> 3) * 8;            // row group 0..63
  const int c0 = (blockIdx.x & 7) * 512;           // col group 0..7

  #pragma unroll
  for(int r=0;r<8;r++)
    for(int k=t;k<INDIM;k+=256) xl_t[k][r] = LD<F32>(x,(size_t)(b0+r)*INDIM+k);
  __syncthreads();

  {
    float acc1[8];
    #pragma unroll
    for(int r=0;r<8;r++) acc1[r]=0.f;
    for(int k0=0;k0<INDIM;k0+=8){
      float wv[8];
      #pragma unroll
      for(int u=0;u<8;u++) wv[u] = LD<F32>(W1,(size_t)(k0+u)*HID+t);
      #pragma unroll
      for(int u=0;u<8;u++){
        float4 xa = *(const float4*)&xl_t[k0+u][0];
        float4 xb = *(const float4*)&xl_t[k0+u][4];
        float w = wv[u];
        acc1[0]+=xa.x*w; acc1[1]+=xa.y*w; acc1[2]+=xa.z*w; acc1[3]+=xa.w*w;
        acc1[4]+=xb.x*w; acc1[5]+=xb.y*w; acc1[6]+=xb.z*w; acc1[7]+=xb.w*w;
      }
    }
    float bb = LD<F32>(b1,t);
    #pragma unroll
    for(int r=0;r<8;r++) hl_t[t][r] = silu(acc1[r]+bb);
  }
  __syncthreads();

  const int colA = c0 + t;                 // <= 3839, always valid
  const int colB = c0 + 256 + t;           // == 4095 invalid only for cg=7,t=255
  const bool okB = (colB < NGEN);
  float acc[8][2];
  {
    float bva = LD<F32>(b2,colA);
    float bvb = okB ? LD<F32>(b2,colB) : 0.f;
    #pragma unroll
    for(int r=0;r<8;r++){ acc[r][0]=bva; acc[r][1]=bvb; }
  }
  for(int k0=0;k0<HID;k0+=8){
    float wa[8], wb[8];
    #pragma unroll
    for(int u=0;u<8;u++){
      wa[u] = LD<F32>(W2,(size_t)(k0+u)*NGEN + colA);
      wb[u] = okB ? LD<F32>(W2,(size_t)(k0+u)*NGEN + colB) : 0.f;
    }
    #pragma unroll
    for(int u=0;u<8;u++){
      float4 ha = *(const float4*)&hl_t[k0+u][0];
      float4 hb = *(const float4*)&hl_t[k0+u][4];
      float fa = wa[u], fb = wb[u];
      acc[0][0]+=ha.x*fa; acc[0][1]+=ha.x*fb;
      acc[1][0]+=ha.y*fa; acc[1][1]+=ha.y*fb;
      acc[2][0]+=ha.z*fa; acc[2][1]+=ha.z*fb;
      acc[3][0]+=ha.w*fa; acc[3][1]+=ha.w*fb;
      acc[4][0]+=hb.x*fa; acc[4][1]+=hb.x*fb;
      acc[5][0]+=hb.y*fa; acc[5][1]+=hb.y*fb;
      acc[6][0]+=hb.z*fa; acc[6][1]+=hb.z*fb;
      acc[7][0]+=hb.w*fa; acc[7][1]+=hb.w*fb;
    }
  }
  #pragma unroll
  for(int r=0;r<8;r++){
    g_theta[(size_t)(b0+r)*NGEN + colA] = acc[r][0];
    if(okB) g_theta[(size_t)(b0+r)*NGEN + colB] = acc[r][1];
  }
}

__global__ __launch_bounds__(256) void k_enc(const void* x,const void* W1,const void* b1,
                                             const void* W2,const void* b2){
  __shared__ __align__(16) float xl_t[INDIM][8];   // 24576 B (shared by both paths)
  __shared__ __align__(16) float hl_t[HID][8];     //  8192 B
  if(g_isf32) enc_body<true >(x,W1,b1,W2,b2,xl_t,hl_t);
  else        enc_body<false>(x,W1,b1,W2,b2,xl_t,hl_t);
}

// -------- state evolution + 2-local observables --------
// R12: ONE WAVE per batch item (block=64, __launch_bounds__(64,2) -> 256-VGPR
// budget).  H is register-resident in XOR-order: hx[2d] = H[lane][lane^d] --
// exactly what the per-pattern WHT leaves in-lane (compile-time d), so no HH
// LDS array and no dynamic register indexing (R8's two failure modes).  The
// Chebyshev K-loop is barrier-free and LDS-free:
//   y_lane = sum_d hx[d] * shfl_xor(v, d);  v,v_prev,psi live per-lane.
// (H/a)e0 is produced by one generic matvec (avoids dynamic hx[2*lane] read).
// LDS: th 16KB (WHT phase) + coef/ps/qacc ~1.9KB -> ~18.3KB/block.
template<bool F32>
__device__ void state_body(const void* __restrict__ Aoff, const void* __restrict__ Boff,
                           const void* __restrict__ Ddiag, char* sm){
  float*  th   = (float*)sm;                 // 16384 B
  float2* coef = (float2*)(sm + 16384);      // 1280 B
  float2* ps   = (float2*)(sm + 17664);      // 512 B
  float*  qacc = (float*)(sm + 18176);       // 64 B

  const int b = blockIdx.x, lane = threadIdx.x;   // 0..63
  for(int m=lane;m<NGEN;m+=64) th[m] = g_theta[(size_t)b*NGEN+m];
  __syncthreads();

  // WHT per xor-pattern d: result at `lane` IS H[lane][lane^d] -> hx[2d],hx[2d+1]
  float hx[128];
  float rsum = 0.f;
  #pragma unroll
  for(int d=0;d<64;d++){
    unsigned td = (unsigned)(lane & d);
    unsigned tn = (unsigned)(lane & ~d) & 63u;
    unsigned w  = spread6((unsigned)d) + spread6(td) + 3u*spread6(tn);
    float thv = (w==0u) ? 0.f : th[w-1u];
    int ny = __popc(td) & 3;                      // phase (-i)^|y|
    float gr = (ny==0)?  thv : (ny==2 ? -thv : 0.f);
    float gi = (ny==1)? -thv : (ny==3 ?  thv : 0.f);
    #pragma unroll
    for(int s=1;s<64;s<<=1){
      float pr = __shfl_xor(gr, s);
      float pi = __shfl_xor(gi, s);
      if(lane & s){ gr = pr - gr; gi = pi - gi; }
      else        { gr = gr + pr; gi = gi + pi; }
    }
    hx[2*d]   = gr;
    hx[2*d+1] = gi;
    rsum += fabsf(gr) + fabsf(gi);
  }

  // spectral bound: max row-sum (row `lane` = all d), wave max-reduce
  #pragma unroll
  for(int s=1;s<64;s<<=1) rsum = fmaxf(rsum, __shfl_xor(rsum, s));
  const float a = fmaxf(rsum, 0.5f);              // wave-uniform
  int K = (int)ceilf(a + 6.f*cbrtf(a) + 10.f);
  if(K>150) K=150;
  const float inva = 1.f/a;

  // Chebyshev coefficients (2-δ) i^k J_k(a), Miller downward (lane 0 -> LDS)
  if(lane==0){
    float bkp=0.f, bk=1e-35f, snorm=0.f;
    for(int k=K+12;k>=1;--k){
      float bkm = (2.f*(float)k/a)*bk - bkp;
      int n = k-1;
      if(n<=K) coef[n].x = bkm;
      if((n&1)==0) snorm += (n==0?1.f:2.f)*bkm;   // J0 + 2*sum J_{2m} = 1
      bkp = bk; bk = bkm;
    }
    float invs = 1.f/snorm;
    for(int n=0;n<=K;n++){
      float cv = coef[n].x*invs*(n==0?1.f:2.f);
      int p = n&3;                                 // i^n
      float cr = (p==0)? cv : (p==2 ? -cv : 0.f);
      float ci = (p==1)? cv : (p==3 ? -cv : 0.f);
      coef[n] = make_float2(cr,ci);
    }
  }
  __syncthreads();

  // T0 = e0; T1 = (H/a)e0 via generic matvec; psi accumulates per-lane
  float v0r = (lane==0)?1.f:0.f, v0i = 0.f;
  float vr, vi;
  {
    float yr=0.f, yi=0.f;
    #pragma unroll
    for(int d=0;d<64;d++){
      float br = __shfl_xor(v0r, d);
      float bi = __shfl_xor(v0i, d);
      float hr = hx[2*d], hi = hx[2*d+1];
      yr += hr*br - hi*bi;
      yi += hr*bi + hi*br;
    }
    vr = yr*inva; vi = yi*inva;
  }
  float2 c0 = coef[0], c1 = coef[1];
  float pr = (lane==0?c0.x:0.f) + c1.x*vr - c1.y*vi;
  float pi = (lane==0?c0.y:0.f) + c1.x*vi + c1.y*vr;

  for(int k=2;k<=K;k++){
    float yr=0.f, yi=0.f;
    #pragma unroll
    for(int d=0;d<64;d++){
      float br = __shfl_xor(vr, d);
      float bi = __shfl_xor(vi, d);
      float hr = hx[2*d], hi = hx[2*d+1];
      yr += hr*br - hi*bi;
      yi += hr*bi + hi*br;
    }
    float nvr = 2.f*inva*yr - v0r;
    float nvi = 2.f*inva*yi - v0i;
    v0r = vr; v0i = vi; vr = nvr; vi = nvi;
    float2 ck = coef[k];
    pr += ck.x*vr - ck.y*vi;
    pi += ck.x*vi + ck.y*vr;
  }
  ps[lane] = make_float2(pr, pi);
  if(lane<NOBS) qacc[lane]=0.f;
  __syncthreads();

  // 2-local observables: 150 tasks over 64 lanes
  for(int task=lane; task<150; task+=64){
    int w = task/10, s = task%10;
    int posA = 5 - c_WA[w], posB = 5 - c_WB[w];
    if(s<4){
      int kk = s;
      if(kk<3){                                   // H_kk = 2*D[w][kk+1]; H_33 = 0
        float val = 0.f;
        for(int r=0;r<16;r++){
          int idx = (((kk>>1)&1)<<posA) | ((kk&1)<<posB);
          int rb = 3;
          #pragma unroll
          for(int p=5;p>=0;--p){
            if(p==posA || p==posB) continue;
            idx |= ((r>>rb)&1)<<p;
            rb--;
          }
          float2 pv = ps[idx];
          val += pv.x*pv.x + pv.y*pv.y;
        }
        atomicAdd(&qacc[w], val*2.f*LD<F32>(Ddiag, w*4 + kk + 1));
      }
    } else {
      int cc = s-4;
      int l = c_Lt[cc], kk = c_Kt[cc];
      float zr=0.f, zi=0.f;
      for(int r=0;r<16;r++){
        int idxk = (((kk>>1)&1)<<posA) | ((kk&1)<<posB);
        int idxl = (((l >>1)&1)<<posA) | ((l &1)<<posB);
        int rb = 3;
        #pragma unroll
        for(int p=5;p>=0;--p){
          if(p==posA || p==posB) continue;
          int bit = (r>>rb)&1;
          idxk |= bit<<p; idxl |= bit<<p;
          rb--;
        }
        float2 pk = ps[idxk], pl = ps[idxl];
        zr += pk.x*pl.x + pk.y*pl.y;              // rho[kk,l]
        zi += pk.y*pl.x - pk.x*pl.y;
      }
      atomicAdd(&qacc[w], 2.f*(zr*LD<F32>(Aoff,w*6+cc) - zi*LD<F32>(Boff,w*6+cc)));
    }
  }
  __syncthreads();
  if(lane<NOBS) g_q[(size_t)b*NOBS + lane] = qacc[lane];
}

__global__ __launch_bounds__(64, 2) void k_state(const void* Aoff,const void* Boff,const void* Dd){
  __shared__ __align__(16) char sm[18240];   // shared by both template paths
  if(g_isf32) state_body<true >(Aoff,Boff,Dd,sm);
  else        state_body<false>(Aoff,Boff,Dd,sm);
}

// ---------------- vel head (UNCHANGED from R10) ----------------
template<bool F32>
__device__ void vel_body(const void* __restrict__ Wv1, const void* __restrict__ bv1,
                         const void* __restrict__ Wv2, const void* __restrict__ bv2,
                         void* __restrict__ out){
  __shared__ float ql[NOBS];
  __shared__ float hl[HID];
  const int b = blockIdx.x, t = threadIdx.x;
  if(t<NOBS) ql[t] = g_q[(size_t)b*NOBS+t];
  __syncthreads();
  float acc = LD<F32>(bv1,t);
  #pragma unroll
  for(int k=0;k<NOBS;k++) acc += ql[k]*LD<F32>(Wv1,k*HID+t);
  hl[t] = silu(acc);
  __syncthreads();
  if(F32){
    #pragma unroll
    for(int oo=0;oo<2;oo++){
      int o = t + oo*256;
      float s0=0.f;
      for(int k=0;k<HID;k++) s0 += hl[k]*LD<F32>(Wv2,(size_t)k*OUTDIM+o);
      ((float*)out)[(size_t)b*OUTDIM+o] = LD<F32>(bv2,o) + s0;
    }
  } else {
    const unsigned* w2p = (const unsigned*)Wv2;     // [256][256] pairs, 4B aligned
    float sa=0.f, sb=0.f;
    #pragma unroll 8
    for(int k=0;k<HID;k++){
      unsigned wp = w2p[(size_t)k*(OUTDIM/2) + t];
      float hk = hl[k];
      sa += hk*__uint_as_float(wp<<16);
      sb += hk*__uint_as_float(wp & 0xFFFF0000u);
    }
    float va = tof(((const bf16*)bv2)[2*t  ]) + sa;
    float vb = tof(((const bf16*)bv2)[2*t+1]) + sb;
    bf16 ha = __float2bfloat16(va), hb = __float2bfloat16(vb);
    unsigned pw = (unsigned)(*(unsigned short*)&ha) | ((unsigned)(*(unsigned short*)&hb)<<16);
    ((unsigned*)out)[(size_t)b*(OUTDIM/2) + t] = pw;
  }
}

__global__ __launch_bounds__(256) void k_vel(const void* Wv1,const void* bv1,
                                             const void* Wv2,const void* bv2, void* out){
  if(g_isf32) vel_body<true >(Wv1,bv1,Wv2,bv2,out);
  else        vel_body<false>(Wv1,bv1,Wv2,bv2,out);
}

extern "C" void kernel_launch(void* const* d_in, const int* in_sizes, int n_in,
                              void* d_out, int out_size, void* d_ws, size_t ws_size,
                              hipStream_t stream){
  const void* x    = d_in[0];
  const void* W1   = d_in[1];
  const void* b1   = d_in[2];
  const void* W2   = d_in[3];
  const void* b2   = d_in[4];
  const void* Aoff = d_in[5];
  const void* Boff = d_in[6];
  const void* Dd   = d_in[7];
  const void* Wv1  = d_in[8];
  const void* bv1  = d_in[9];
  const void* Wv2  = d_in[10];
  const void* bv2  = d_in[11];
  // d_in[12] (pauli) unused: H_eff built analytically from the Pauli-word structure.

  k_detect<<<1,256,0,stream>>>((const unsigned*)W1);
  k_enc  <<<512,256,0,stream>>>(x,W1,b1,W2,b2);
  k_state<<<BATCH,64,0,stream>>>(Aoff,Boff,Dd);
  k_vel  <<<BATCH,256,0,stream>>>(Wv1,bv1,Wv2,bv2,d_out);
}

// Round 13
// 313.746 us; speedup vs baseline: 1.5520x; 1.5520x over previous
//
#include <hip/hip_runtime.h>
#include <hip/hip_bf16.h>

#define BATCH   512
#define INDIM   768
#define HID     256
#define NGEN    4095
#define NOBS    15
#define OUTDIM  512
#define DIM     64

typedef __hip_bfloat16 bf16;

// static device scratch: no reliance on ws_size
__device__ int   g_isf32;
__device__ float g_theta[(size_t)BATCH*NGEN];
__device__ float g_q[BATCH*NOBS];

__device__ __forceinline__ float tof(bf16 v){ return __bfloat162float(v); }
__device__ __forceinline__ float silu(float x){ return x / (1.f + __expf(-x)); }

template<bool F32>
__device__ __forceinline__ float LD(const void* p, size_t i){
  if(F32) return ((const float*)p)[i];
  else    return tof(((const bf16*)p)[i]);
}

// put bit p of x at bit 2p (6-bit input)
__device__ __forceinline__ unsigned spread6(unsigned x){
  return (x&1u) | ((x&2u)<<1) | ((x&4u)<<2) | ((x&8u)<<3) | ((x&16u)<<4) | ((x&32u)<<5);
}

__constant__ int c_WA[15] = {0,0,0,0,0,1,1,1,1,2,2,2,3,3,4};
__constant__ int c_WB[15] = {1,2,3,4,5,2,3,4,5,3,4,5,4,5,5};
__constant__ int c_Lt[6]  = {1,2,2,3,3,3};
__constant__ int c_Kt[6]  = {0,0,1,0,1,2};

// ---- dtype sniffer (UNCHANGED; stays the FIRST kernel) ----
__global__ __launch_bounds__(256) void k_detect(const unsigned* __restrict__ w1raw){
  __shared__ int sh[256];
  const int t = threadIdx.x;
  int c = 0;
  for(int i=t;i<1024;i+=256){
    unsigned ub = (w1raw[i]>>8) & 0x7Fu;
    if(ub>=0x30u && ub<=0x3Fu) c++;
  }
  sh[t] = c;
  __syncthreads();
  for(int s=128;s>0;s>>=1){
    if(t<s) sh[t] += sh[t+s];
    __syncthreads();
  }
  if(t==0) g_isf32 = (sh[0] < 512) ? 1 : 0;
}

// ---------------- enc MLP: theta = silu(x@W1+b1)@W2+b2 ----------------
// R13: 1024 blocks (was 512) = 128 row-groups (4 rows) x 8 col-groups (512
// cols, 2 cols/thread).  2 -> 4 blocks/CU: R10's enc was latency-bound on
// ~96 serial L2-load rounds with only 2 blocks/CU of overlap.  Phase-1 work
// per block halves; W1 re-read doubles but is L2-resident (~49MB aggregate).
template<bool F32>
__device__ void enc_body(const void* __restrict__ x, const void* __restrict__ W1,
                         const void* __restrict__ b1, const void* __restrict__ W2,
                         const void* __restrict__ b2,
                         float (*xl_t)[4], float (*hl_t)[4]){
  const int t  = threadIdx.x;
  const int b0 = (blockIdx.x >> 3) * 4;            // row group 0..127
  const int c0 = (blockIdx.x & 7) * 512;           // col group 0..7

  #pragma unroll
  for(int r=0;r<4;r++)
    for(int k=t;k<INDIM;k+=256) xl_t[k][r] = LD<F32>(x,(size_t)(b0+r)*INDIM+k);
  __syncthreads();

  {
    float acc1[4]={0.f,0.f,0.f,0.f};
    for(int k0=0;k0<INDIM;k0+=8){
      float wv[8];
      #pragma unroll
      for(int u=0;u<8;u++) wv[u] = LD<F32>(W1,(size_t)(k0+u)*HID+t);
      #pragma unroll
      for(int u=0;u<8;u++){
        float4 xa = *(const float4*)&xl_t[k0+u][0];
        float w = wv[u];
        acc1[0]+=xa.x*w; acc1[1]+=xa.y*w; acc1[2]+=xa.z*w; acc1[3]+=xa.w*w;
      }
    }
    float bb = LD<F32>(b1,t);
    #pragma unroll
    for(int r=0;r<4;r++) hl_t[t][r] = silu(acc1[r]+bb);
  }
  __syncthreads();

  const int colA = c0 + t;                 // <= 3839, always valid
  const int colB = c0 + 256 + t;           // == 4095 invalid only for cg=7,t=255
  const bool okB = (colB < NGEN);
  float acc[4][2];
  {
    float bva = LD<F32>(b2,colA);
    float bvb = okB ? LD<F32>(b2,colB) : 0.f;
    #pragma unroll
    for(int r=0;r<4;r++){ acc[r][0]=bva; acc[r][1]=bvb; }
  }
  for(int k0=0;k0<HID;k0+=8){
    float wa[8], wb[8];
    #pragma unroll
    for(int u=0;u<8;u++){
      wa[u] = LD<F32>(W2,(size_t)(k0+u)*NGEN + colA);
      wb[u] = okB ? LD<F32>(W2,(size_t)(k0+u)*NGEN + colB) : 0.f;
    }
    #pragma unroll
    for(int u=0;u<8;u++){
      float4 ha = *(const float4*)&hl_t[k0+u][0];
      float fa = wa[u], fb = wb[u];
      acc[0][0]+=ha.x*fa; acc[0][1]+=ha.x*fb;
      acc[1][0]+=ha.y*fa; acc[1][1]+=ha.y*fb;
      acc[2][0]+=ha.z*fa; acc[2][1]+=ha.z*fb;
      acc[3][0]+=ha.w*fa; acc[3][1]+=ha.w*fb;
    }
  }
  #pragma unroll
  for(int r=0;r<4;r++){
    g_theta[(size_t)(b0+r)*NGEN + colA] = acc[r][0];
    if(okB) g_theta[(size_t)(b0+r)*NGEN + colB] = acc[r][1];
  }
}

__global__ __launch_bounds__(256) void k_enc(const void* x,const void* W1,const void* b1,
                                             const void* W2,const void* b2){
  __shared__ __align__(16) float xl_t[INDIM][4];   // 12288 B (shared by both paths)
  __shared__ __align__(16) float hl_t[HID][4];     //  4096 B
  if(g_isf32) enc_body<true >(x,W1,b1,W2,b2,xl_t,hl_t);
  else        enc_body<false>(x,W1,b1,W2,b2,xl_t,hl_t);
}

// -------- state evolution + 2-local observables (R11 body VERBATIM — proven
// 118.5us; R12's register-resident variant spilled at VGPR=128 and regressed) --------
template<bool F32>
__device__ void state_body(const void* __restrict__ Aoff, const void* __restrict__ Boff,
                           const void* __restrict__ Ddiag, char* sm){
  float*  th   = (float*)sm;                       // 4096 f  (dead after WHT)
  float*  HH   = (float*)(sm + 16384);             // 64*132 f
  typedef float2 rep_t[66];
  rep_t*  vrA  = (rep_t*)sm;                       // 4*66 f2 = 2112 B
  rep_t*  vrB  = (rep_t*)(sm + 2112);              // 2112 B
  float2* ps   = (float2*)(sm + 4224);             // 512 B
  float2* coef = (float2*)(sm + 4736);             // 1280 B
  float*  rs   = (float*)(sm + 6016);              // 256 B
  float*  qacc = (float*)(sm + 6272);              // 64 B
  float*  s_inva = (float*)(sm + 6336);
  int*    s_K    = (int*)(sm + 6340);

  const int b = blockIdx.x, t = threadIdx.x;
  for(int m=t;m<NGEN;m+=256) th[m] = g_theta[(size_t)b*NGEN+m];
  __syncthreads();

  const int lane = t & 63, wav = t >> 6;
  for(int it=0; it<16; ++it){
    int d = (it<<2) | wav;
    unsigned td = (unsigned)(lane & d);
    unsigned tn = (unsigned)(lane & ~d) & 63u;
    unsigned w  = spread6((unsigned)d) + spread6(td) + 3u*spread6(tn);
    float thv = (w==0u) ? 0.f : th[w-1u];
    int ny = __popc(td) & 3;
    float gr = (ny==0)?  thv : (ny==2 ? -thv : 0.f);
    float gi = (ny==1)? -thv : (ny==3 ?  thv : 0.f);
    #pragma unroll
    for(int s=1;s<64;s<<=1){
      float pr = __shfl_xor(gr, s);
      float pi = __shfl_xor(gi, s);
      if(lane & s){ gr = pr - gr; gi = pi - gi; }
      else        { gr = gr + pr; gi = gi + pi; }
    }
    int j = lane ^ d;
    HH[lane*132 + 2*j]   = gr;
    HH[lane*132 + 2*j+1] = gi;
  }
  __syncthreads();          // th dead from here; its region now holds vrA..s_K

  const int i = t >> 2, c = t & 3, j0 = c*16;
  float hreg[32];
  float rsum = 0.f;
  #pragma unroll
  for(int jj=0;jj<16;jj+=2){
    float4 hv = *(const float4*)&HH[i*132 + 2*(j0+jj)];
    hreg[2*jj+0]=hv.x; hreg[2*jj+1]=hv.y; hreg[2*jj+2]=hv.z; hreg[2*jj+3]=hv.w;
    rsum += fabsf(hv.x)+fabsf(hv.y)+fabsf(hv.z)+fabsf(hv.w);
  }
  rsum += __shfl_xor(rsum,1);
  rsum += __shfl_xor(rsum,2);
  if(c==0) rs[i] = rsum;
  __syncthreads();

  if(t==0){
    float a = 0.5f;
    for(int r=0;r<DIM;r++) a = fmaxf(a, rs[r]);
    int K = (int)ceilf(a + 6.f*cbrtf(a) + 10.f);
    if(K>150) K=150;
    float bkp=0.f, bk=1e-35f, snorm=0.f;
    for(int k=K+12;k>=1;--k){
      float bkm = (2.f*(float)k/a)*bk - bkp;
      int n = k-1;
      if(n<=K) coef[n].x = bkm;
      if((n&1)==0) snorm += (n==0?1.f:2.f)*bkm;
      bkp = bk; bk = bkm;
    }
    float invs = 1.f/snorm;
    for(int n=0;n<=K;n++){
      float cv = coef[n].x*invs*(n==0?1.f:2.f);
      int p = n&3;
      float cr = (p==0)? cv : (p==2 ? -cv : 0.f);
      float ci = (p==1)? cv : (p==3 ? -cv : 0.f);
      coef[n] = make_float2(cr,ci);
    }
    *s_K = K;
    *s_inva = 1.f/a;
  }
  __syncthreads();
  const float inva = *s_inva;
  const int K = *s_K;

  rep_t* v0r = vrA;
  rep_t* v1r = vrB;
  if(t < DIM){
    float2 w1 = make_float2(HH[t*132+0]*inva, HH[t*132+1]*inva);
    float2 e0 = make_float2(t==0?1.f:0.f, 0.f);
    #pragma unroll
    for(int cc=0;cc<4;cc++){ v0r[cc][t] = e0; v1r[cc][t] = w1; }
    float2 c0 = coef[0], c1 = coef[1];
    float2 p;
    p.x = (t==0?c0.x:0.f) + c1.x*w1.x - c1.y*w1.y;
    p.y = (t==0?c0.y:0.f) + c1.x*w1.y + c1.y*w1.x;
    ps[t] = p;
  }
  __syncthreads();

  for(int k=2;k<=K;k++){
    const float* vb = (const float*)&v1r[c][0];   // copy c: base bank 4c -> no conflicts
    float yr=0.f, yi=0.f;
    #pragma unroll
    for(int jj=0;jj<16;jj+=2){
      float4 xv = *(const float4*)&vb[2*(j0+jj)];
      float hr0=hreg[2*jj], hi0=hreg[2*jj+1], hr1=hreg[2*jj+2], hi1=hreg[2*jj+3];
      yr += hr0*xv.x - hi0*xv.y;
      yi += hr0*xv.y + hi0*xv.x;
      yr += hr1*xv.z - hi1*xv.w;
      yi += hr1*xv.w + hi1*xv.z;
    }
    yr += __shfl_xor(yr,1); yr += __shfl_xor(yr,2);
    yi += __shfl_xor(yi,1); yi += __shfl_xor(yi,2);
    if(c==0){
      float2 vm = v0r[0][i];
      float2 vn = make_float2(2.f*inva*yr - vm.x, 2.f*inva*yi - vm.y);
      #pragma unroll
      for(int cc=0;cc<4;cc++) v0r[cc][i] = vn;    // becomes v1 after swap
      float2 ck = coef[k];
      float2 p = ps[i];
      p.x += ck.x*vn.x - ck.y*vn.y;
      p.y += ck.x*vn.y + ck.y*vn.x;
      ps[i] = p;
    }
    __syncthreads();
    rep_t* tmp = v0r; v0r = v1r; v1r = tmp;
  }

  if(t<NOBS) qacc[t]=0.f;
  __syncthreads();

  if(t<150){
    int w = t/10, s = t%10;
    int posA = 5 - c_WA[w], posB = 5 - c_WB[w];
    float contrib = 0.f;
    bool have = false;
    if(s<4){
      int kk = s;
      if(kk<3){
        float val = 0.f;
        for(int r=0;r<16;r++){
          int idx = (((kk>>1)&1)<<posA) | ((kk&1)<<posB);
          int rb = 3;
          #pragma unroll
          for(int p=5;p>=0;--p){
            if(p==posA || p==posB) continue;
            idx |= ((r>>rb)&1)<<p;
            rb--;
          }
          float2 pv = ps[idx];
          val += pv.x*pv.x + pv.y*pv.y;
        }
        contrib = val*2.f*LD<F32>(Ddiag, w*4 + kk + 1);
        have = true;
      }
    } else {
      int cc = s-4;
      int l = c_Lt[cc], kk = c_Kt[cc];
      float zr=0.f, zi=0.f;
      for(int r=0;r<16;r++){
        int idxk = (((kk>>1)&1)<<posA) | ((kk&1)<<posB);
        int idxl = (((l >>1)&1)<<posA) | ((l &1)<<posB);
        int rb = 3;
        #pragma unroll
        for(int p=5;p>=0;--p){
          if(p==posA || p==posB) continue;
          int bit = (r>>rb)&1;
          idxk |= bit<<p; idxl |= bit<<p;
          rb--;
        }
        float2 pk = ps[idxk], pl = ps[idxl];
        zr += pk.x*pl.x + pk.y*pl.y;
        zi += pk.y*pl.x - pk.x*pl.y;
      }
      contrib = 2.f*(zr*LD<F32>(Aoff,w*6+cc) - zi*LD<F32>(Boff,w*6+cc));
      have = true;
    }
    if(have) atomicAdd(&qacc[w], contrib);
  }
  __syncthreads();
  if(t<NOBS) g_q[(size_t)b*NOBS + t] = qacc[t];
}

__global__ __launch_bounds__(256) void k_state(const void* Aoff,const void* Boff,const void* Dd){
  __shared__ __align__(16) char sm[50176];   // shared by both template paths
  if(g_isf32) state_body<true >(Aoff,Boff,Dd,sm);
  else        state_body<false>(Aoff,Boff,Dd,sm);
}

// ---------------- vel head (UNCHANGED from R10) ----------------
template<bool F32>
__device__ void vel_body(const void* __restrict__ Wv1, const void* __restrict__ bv1,
                         const void* __restrict__ Wv2, const void* __restrict__ bv2,
                         void* __restrict__ out){
  __shared__ float ql[NOBS];
  __shared__ float hl[HID];
  const int b = blockIdx.x, t = threadIdx.x;
  if(t<NOBS) ql[t] = g_q[(size_t)b*NOBS+t];
  __syncthreads();
  float acc = LD<F32>(bv1,t);
  #pragma unroll
  for(int k=0;k<NOBS;k++) acc += ql[k]*LD<F32>(Wv1,k*HID+t);
  hl[t] = silu(acc);
  __syncthreads();
  if(F32){
    #pragma unroll
    for(int oo=0;oo<2;oo++){
      int o = t + oo*256;
      float s0=0.f;
      for(int k=0;k<HID;k++) s0 += hl[k]*LD<F32>(Wv2,(size_t)k*OUTDIM+o);
      ((float*)out)[(size_t)b*OUTDIM+o] = LD<F32>(bv2,o) + s0;
    }
  } else {
    const unsigned* w2p = (const unsigned*)Wv2;     // [256][256] pairs, 4B aligned
    float sa=0.f, sb=0.f;
    #pragma unroll 8
    for(int k=0;k<HID;k++){
      unsigned wp = w2p[(size_t)k*(OUTDIM/2) + t];
      float hk = hl[k];
      sa += hk*__uint_as_float(wp<<16);
      sb += hk*__uint_as_float(wp & 0xFFFF0000u);
    }
    float va = tof(((const bf16*)bv2)[2*t  ]) + sa;
    float vb = tof(((const bf16*)bv2)[2*t+1]) + sb;
    bf16 ha = __float2bfloat16(va), hb = __float2bfloat16(vb);
    unsigned pw = (unsigned)(*(unsigned short*)&ha) | ((unsigned)(*(unsigned short*)&hb)<<16);
    ((unsigned*)out)[(size_t)b*(OUTDIM/2) + t] = pw;
  }
}

__global__ __launch_bounds__(256) void k_vel(const void* Wv1,const void* bv1,
                                             const void* Wv2,const void* bv2, void* out){
  if(g_isf32) vel_body<true >(Wv1,bv1,Wv2,bv2,out);
  else        vel_body<false>(Wv1,bv1,Wv2,bv2,out);
}

extern "C" void kernel_launch(void* const* d_in, const int* in_sizes, int n_in,
                              void* d_out, int out_size, void* d_ws, size_t ws_size,
                              hipStream_t stream){
  const void* x    = d_in[0];
  const void* W1   = d_in[1];
  const void* b1   = d_in[2];
  const void* W2   = d_in[3];
  const void* b2   = d_in[4];
  const void* Aoff = d_in[5];
  const void* Boff = d_in[6];
  const void* Dd   = d_in[7];
  const void* Wv1  = d_in[8];
  const void* bv1  = d_in[9];
  const void* Wv2  = d_in[10];
  const void* bv2  = d_in[11];
  // d_in[12] (pauli) unused: H_eff built analytically from the Pauli-word structure.

  k_detect<<<1,256,0,stream>>>((const unsigned*)W1);
  k_enc  <<<1024,256,0,stream>>>(x,W1,b1,W2,b2);
  k_state<<<BATCH,256,0,stream>>>(Aoff,Boff,Dd);
  k_vel  <<<BATCH,256,0,stream>>>(Wv1,bv1,Wv2,bv2,d_out);
}

// Round 14
// 312.515 us; speedup vs baseline: 1.5581x; 1.0039x over previous
//
#include <hip/hip_runtime.h>
#include <hip/hip_bf16.h>

#define BATCH   512
#define INDIM   768
#define HID     256
#define NGEN    4095
#define NOBS    15
#define OUTDIM  512
#define DIM     64

typedef __hip_bfloat16 bf16;

// static device scratch: no reliance on ws_size
__device__ int      g_isf32;
__device__ float    g_theta[(size_t)BATCH*NGEN];
__device__ float    g_q[BATCH*NOBS];
__device__ unsigned g_out[(size_t)BATCH*(OUTDIM/2)];   // bf16-pair packed output

__device__ __forceinline__ float tof(bf16 v){ return __bfloat162float(v); }
__device__ __forceinline__ float silu(float x){ return x / (1.f + __expf(-x)); }
__device__ __forceinline__ float blo(unsigned u){ return __uint_as_float(u<<16); }
__device__ __forceinline__ float bhi(unsigned u){ return __uint_as_float(u & 0xFFFF0000u); }

template<bool F32>
__device__ __forceinline__ float LD(const void* p, size_t i){
  if(F32) return ((const float*)p)[i];
  else    return tof(((const bf16*)p)[i]);
}

// put bit p of x at bit 2p (6-bit input)
__device__ __forceinline__ unsigned spread6(unsigned x){
  return (x&1u) | ((x&2u)<<1) | ((x&4u)<<2) | ((x&8u)<<3) | ((x&16u)<<4) | ((x&32u)<<5);
}

__constant__ int c_WA[15] = {0,0,0,0,0,1,1,1,1,2,2,2,3,3,4};
__constant__ int c_WB[15] = {1,2,3,4,5,2,3,4,5,3,4,5,4,5,5};
__constant__ int c_Lt[6]  = {1,2,2,3,3,3};
__constant__ int c_Kt[6]  = {0,0,1,0,1,2};

// ---- dtype sniffer (UNCHANGED; stays the FIRST kernel) ----
__global__ __launch_bounds__(256) void k_detect(const unsigned* __restrict__ w1raw){
  __shared__ int sh[256];
  const int t = threadIdx.x;
  int c = 0;
  for(int i=t;i<1024;i+=256){
    unsigned ub = (w1raw[i]>>8) & 0x7Fu;
    if(ub>=0x30u && ub<=0x3Fu) c++;
  }
  sh[t] = c;
  __syncthreads();
  for(int s=128;s>0;s>>=1){
    if(t<s) sh[t] += sh[t+s];
    __syncthreads();
  }
  if(t==0) g_isf32 = (sh[0] < 512) ? 1 : 0;
}

// ---------------- enc MLP (UNCHANGED R13 body) ----------------
template<bool F32>
__device__ void enc_body(const void* __restrict__ x, const void* __restrict__ W1,
                         const void* __restrict__ b1, const void* __restrict__ W2,
                         const void* __restrict__ b2,
                         float (*xl_t)[4], float (*hl_t)[4]){
  const int t  = threadIdx.x;
  const int b0 = (blockIdx.x >> 3) * 4;            // row group 0..127
  const int c0 = (blockIdx.x & 7) * 512;           // col group 0..7

  #pragma unroll
  for(int r=0;r<4;r++)
    for(int k=t;k<INDIM;k+=256) xl_t[k][r] = LD<F32>(x,(size_t)(b0+r)*INDIM+k);
  __syncthreads();

  {
    float acc1[4]={0.f,0.f,0.f,0.f};
    for(int k0=0;k0<INDIM;k0+=8){
      float wv[8];
      #pragma unroll
      for(int u=0;u<8;u++) wv[u] = LD<F32>(W1,(size_t)(k0+u)*HID+t);
      #pragma unroll
      for(int u=0;u<8;u++){
        float4 xa = *(const float4*)&xl_t[k0+u][0];
        float w = wv[u];
        acc1[0]+=xa.x*w; acc1[1]+=xa.y*w; acc1[2]+=xa.z*w; acc1[3]+=xa.w*w;
      }
    }
    float bb = LD<F32>(b1,t);
    #pragma unroll
    for(int r=0;r<4;r++) hl_t[t][r] = silu(acc1[r]+bb);
  }
  __syncthreads();

  const int colA = c0 + t;
  const int colB = c0 + 256 + t;
  const bool okB = (colB < NGEN);
  float acc[4][2];
  {
    float bva = LD<F32>(b2,colA);
    float bvb = okB ? LD<F32>(b2,colB) : 0.f;
    #pragma unroll
    for(int r=0;r<4;r++){ acc[r][0]=bva; acc[r][1]=bvb; }
  }
  for(int k0=0;k0<HID;k0+=8){
    float wa[8], wb[8];
    #pragma unroll
    for(int u=0;u<8;u++){
      wa[u] = LD<F32>(W2,(size_t)(k0+u)*NGEN + colA);
      wb[u] = okB ? LD<F32>(W2,(size_t)(k0+u)*NGEN + colB) : 0.f;
    }
    #pragma unroll
    for(int u=0;u<8;u++){
      float4 ha = *(const float4*)&hl_t[k0+u][0];
      float fa = wa[u], fb = wb[u];
      acc[0][0]+=ha.x*fa; acc[0][1]+=ha.x*fb;
      acc[1][0]+=ha.y*fa; acc[1][1]+=ha.y*fb;
      acc[2][0]+=ha.z*fa; acc[2][1]+=ha.z*fb;
      acc[3][0]+=ha.w*fa; acc[3][1]+=ha.w*fb;
    }
  }
  #pragma unroll
  for(int r=0;r<4;r++){
    g_theta[(size_t)(b0+r)*NGEN + colA] = acc[r][0];
    if(okB) g_theta[(size_t)(b0+r)*NGEN + colB] = acc[r][1];
  }
}

__global__ __launch_bounds__(256) void k_enc(const void* x,const void* W1,const void* b1,
                                             const void* W2,const void* b2){
  __shared__ __align__(16) float xl_t[INDIM][4];
  __shared__ __align__(16) float hl_t[HID][4];
  if(g_isf32) enc_body<true >(x,W1,b1,W2,b2,xl_t,hl_t);
  else        enc_body<false>(x,W1,b1,W2,b2,xl_t,hl_t);
}

// -------- state evolution + observables + FUSED vel head (R14) --------
// R11 body verbatim through the observables; then (bf16 path only) the vel
// head runs in-block: block b owns q[b] in LDS, so h=silu(q@Wv1+bv1) and
// out=h@Wv2+bv2 are computed here with uint4 (8x bf16) Wv2 loads -- 64
// loads/thread (vs standalone k_vel's 256) that overlap other resident
// blocks' Chebyshev compute.  Result packed to g_out; k_vel just copies.
template<bool F32>
__device__ void state_body(const void* __restrict__ Aoff, const void* __restrict__ Boff,
                           const void* __restrict__ Ddiag,
                           const void* __restrict__ Wv1, const void* __restrict__ bv1,
                           const void* __restrict__ Wv2, const void* __restrict__ bv2,
                           char* sm){
  float*  th   = (float*)sm;                       // 16KB region, dead after WHT
  float*  HH   = (float*)(sm + 16384);             // 64*132 f
  typedef float2 rep_t[66];
  rep_t*  vrA  = (rep_t*)sm;                       // 2112 B
  rep_t*  vrB  = (rep_t*)(sm + 2112);              // 2112 B
  float2* ps   = (float2*)(sm + 4224);             // 512 B
  float2* coef = (float2*)(sm + 4736);             // 1280 B
  float*  rs   = (float*)(sm + 6016);              // 256 B
  float*  qacc = (float*)(sm + 6272);              // 64 B
  float*  s_inva = (float*)(sm + 6336);
  int*    s_K    = (int*)(sm + 6340);
  float*  hl   = (float*)(sm + 6400);              // 1KB   (fused vel)
  float (*part)[64][8] = (float(*)[64][8])(sm + 7424); // 8KB (fused vel) -> 15616 < 16384

  const int b = blockIdx.x, t = threadIdx.x;
  for(int m=t;m<NGEN;m+=256) th[m] = g_theta[(size_t)b*NGEN+m];
  __syncthreads();

  const int lane = t & 63, wav = t >> 6;
  for(int it=0; it<16; ++it){
    int d = (it<<2) | wav;
    unsigned td = (unsigned)(lane & d);
    unsigned tn = (unsigned)(lane & ~d) & 63u;
    unsigned w  = spread6((unsigned)d) + spread6(td) + 3u*spread6(tn);
    float thv = (w==0u) ? 0.f : th[w-1u];
    int ny = __popc(td) & 3;
    float gr = (ny==0)?  thv : (ny==2 ? -thv : 0.f);
    float gi = (ny==1)? -thv : (ny==3 ?  thv : 0.f);
    #pragma unroll
    for(int s=1;s<64;s<<=1){
      float pr = __shfl_xor(gr, s);
      float pi = __shfl_xor(gi, s);
      if(lane & s){ gr = pr - gr; gi = pi - gi; }
      else        { gr = gr + pr; gi = gi + pi; }
    }
    int j = lane ^ d;
    HH[lane*132 + 2*j]   = gr;
    HH[lane*132 + 2*j+1] = gi;
  }
  __syncthreads();          // th region dead; small buffers live there now

  const int i = t >> 2, c = t & 3, j0 = c*16;
  float hreg[32];
  float rsum = 0.f;
  #pragma unroll
  for(int jj=0;jj<16;jj+=2){
    float4 hv = *(const float4*)&HH[i*132 + 2*(j0+jj)];
    hreg[2*jj+0]=hv.x; hreg[2*jj+1]=hv.y; hreg[2*jj+2]=hv.z; hreg[2*jj+3]=hv.w;
    rsum += fabsf(hv.x)+fabsf(hv.y)+fabsf(hv.z)+fabsf(hv.w);
  }
  rsum += __shfl_xor(rsum,1);
  rsum += __shfl_xor(rsum,2);
  if(c==0) rs[i] = rsum;
  __syncthreads();

  if(t==0){
    float a = 0.5f;
    for(int r=0;r<DIM;r++) a = fmaxf(a, rs[r]);
    int K = (int)ceilf(a + 6.f*cbrtf(a) + 10.f);
    if(K>150) K=150;
    float bkp=0.f, bk=1e-35f, snorm=0.f;
    for(int k=K+12;k>=1;--k){
      float bkm = (2.f*(float)k/a)*bk - bkp;
      int n = k-1;
      if(n<=K) coef[n].x = bkm;
      if((n&1)==0) snorm += (n==0?1.f:2.f)*bkm;
      bkp = bk; bk = bkm;
    }
    float invs = 1.f/snorm;
    for(int n=0;n<=K;n++){
      float cv = coef[n].x*invs*(n==0?1.f:2.f);
      int p = n&3;
      float cr = (p==0)? cv : (p==2 ? -cv : 0.f);
      float ci = (p==1)? cv : (p==3 ? -cv : 0.f);
      coef[n] = make_float2(cr,ci);
    }
    *s_K = K;
    *s_inva = 1.f/a;
  }
  __syncthreads();
  const float inva = *s_inva;
  const int K = *s_K;

  rep_t* v0r = vrA;
  rep_t* v1r = vrB;
  if(t < DIM){
    float2 w1 = make_float2(HH[t*132+0]*inva, HH[t*132+1]*inva);
    float2 e0 = make_float2(t==0?1.f:0.f, 0.f);
    #pragma unroll
    for(int cc=0;cc<4;cc++){ v0r[cc][t] = e0; v1r[cc][t] = w1; }
    float2 c0 = coef[0], c1 = coef[1];
    float2 p;
    p.x = (t==0?c0.x:0.f) + c1.x*w1.x - c1.y*w1.y;
    p.y = (t==0?c0.y:0.f) + c1.x*w1.y + c1.y*w1.x;
    ps[t] = p;
  }
  __syncthreads();

  for(int k=2;k<=K;k++){
    const float* vb = (const float*)&v1r[c][0];
    float yr=0.f, yi=0.f;
    #pragma unroll
    for(int jj=0;jj<16;jj+=2){
      float4 xv = *(const float4*)&vb[2*(j0+jj)];
      float hr0=hreg[2*jj], hi0=hreg[2*jj+1], hr1=hreg[2*jj+2], hi1=hreg[2*jj+3];
      yr += hr0*xv.x - hi0*xv.y;
      yi += hr0*xv.y + hi0*xv.x;
      yr += hr1*xv.z - hi1*xv.w;
      yi += hr1*xv.w + hi1*xv.z;
    }
    yr += __shfl_xor(yr,1); yr += __shfl_xor(yr,2);
    yi += __shfl_xor(yi,1); yi += __shfl_xor(yi,2);
    if(c==0){
      float2 vm = v0r[0][i];
      float2 vn = make_float2(2.f*inva*yr - vm.x, 2.f*inva*yi - vm.y);
      #pragma unroll
      for(int cc=0;cc<4;cc++) v0r[cc][i] = vn;
      float2 ck = coef[k];
      float2 p = ps[i];
      p.x += ck.x*vn.x - ck.y*vn.y;
      p.y += ck.x*vn.y + ck.y*vn.x;
      ps[i] = p;
    }
    __syncthreads();
    rep_t* tmp = v0r; v0r = v1r; v1r = tmp;
  }

  if(t<NOBS) qacc[t]=0.f;
  __syncthreads();

  if(t<150){
    int w = t/10, s = t%10;
    int posA = 5 - c_WA[w], posB = 5 - c_WB[w];
    float contrib = 0.f;
    bool have = false;
    if(s<4){
      int kk = s;
      if(kk<3){
        float val = 0.f;
        for(int r=0;r<16;r++){
          int idx = (((kk>>1)&1)<<posA) | ((kk&1)<<posB);
          int rb = 3;
          #pragma unroll
          for(int p=5;p>=0;--p){
            if(p==posA || p==posB) continue;
            idx |= ((r>>rb)&1)<<p;
            rb--;
          }
          float2 pv = ps[idx];
          val += pv.x*pv.x + pv.y*pv.y;
        }
        contrib = val*2.f*LD<F32>(Ddiag, w*4 + kk + 1);
        have = true;
      }
    } else {
      int cc = s-4;
      int l = c_Lt[cc], kk = c_Kt[cc];
      float zr=0.f, zi=0.f;
      for(int r=0;r<16;r++){
        int idxk = (((kk>>1)&1)<<posA) | ((kk&1)<<posB);
        int idxl = (((l >>1)&1)<<posA) | ((l &1)<<posB);
        int rb = 3;
        #pragma unroll
        for(int p=5;p>=0;--p){
          if(p==posA || p==posB) continue;
          int bit = (r>>rb)&1;
          idxk |= bit<<p; idxl |= bit<<p;
          rb--;
        }
        float2 pk = ps[idxk], pl = ps[idxl];
        zr += pk.x*pl.x + pk.y*pl.y;
        zi += pk.y*pl.x - pk.x*pl.y;
      }
      contrib = 2.f*(zr*LD<F32>(Aoff,w*6+cc) - zi*LD<F32>(Boff,w*6+cc));
      have = true;
    }
    if(have) atomicAdd(&qacc[w], contrib);
  }
  __syncthreads();
  if(t<NOBS) g_q[(size_t)b*NOBS + t] = qacc[t];

  // ---------- FUSED vel head (bf16 path only; f32 path uses old k_vel) ----------
  if(!F32){
    // h[t] = silu(bv1[t] + sum_k q[k]*Wv1[k][t])
    {
      float acc = tof(((const bf16*)bv1)[t]);
      #pragma unroll
      for(int k=0;k<NOBS;k++) acc += qacc[k]*tof(((const bf16*)Wv1)[k*HID+t]);
      hl[t] = silu(acc);
    }
    __syncthreads();
    // out = h @ Wv2 + bv2 : 8 cols/lane x 4 k-chunks, uint4 loads (8 bf16)
    const int rg = t >> 6;                     // k-chunk 0..3
    const uint4* w2v = (const uint4*)Wv2;      // row = 64 uint4 (512 cols)
    float a8[8] = {0.f,0.f,0.f,0.f,0.f,0.f,0.f,0.f};
    for(int kk=0; kk<64; kk+=8){
      uint4 wv[8];
      #pragma unroll
      for(int u=0;u<8;u++) wv[u] = w2v[(size_t)(rg*64+kk+u)*64 + lane];
      #pragma unroll
      for(int u=0;u<8;u++){
        float hk = hl[rg*64+kk+u];
        a8[0] += hk*blo(wv[u].x); a8[1] += hk*bhi(wv[u].x);
        a8[2] += hk*blo(wv[u].y); a8[3] += hk*bhi(wv[u].y);
        a8[4] += hk*blo(wv[u].z); a8[5] += hk*bhi(wv[u].z);
        a8[6] += hk*blo(wv[u].w); a8[7] += hk*bhi(wv[u].w);
      }
    }
    #pragma unroll
    for(int j=0;j<8;j++) part[rg][lane][j] = a8[j];
    __syncthreads();
    // reduce partials; thread t -> cols {2t, 2t+1}; pack bf16 pair
    {
      int cA = 2*t, cB = 2*t+1;
      float vA = tof(((const bf16*)bv2)[cA]);
      float vB = tof(((const bf16*)bv2)[cB]);
      #pragma unroll
      for(int r2=0;r2<4;r2++){
        vA += part[r2][cA>>3][cA&7];
        vB += part[r2][cB>>3][cB&7];
      }
      bf16 ha = __float2bfloat16(vA), hb = __float2bfloat16(vB);
      unsigned pw = (unsigned)(*(unsigned short*)&ha) |
                    ((unsigned)(*(unsigned short*)&hb)<<16);
      g_out[(size_t)b*(OUTDIM/2) + t] = pw;
    }
  }
}

__global__ __launch_bounds__(256) void k_state(const void* Aoff,const void* Boff,const void* Dd,
                                               const void* Wv1,const void* bv1,
                                               const void* Wv2,const void* bv2){
  __shared__ __align__(16) char sm[50176];   // shared by both template paths
  if(g_isf32) state_body<true >(Aoff,Boff,Dd,Wv1,bv1,Wv2,bv2,sm);
  else        state_body<false>(Aoff,Boff,Dd,Wv1,bv1,Wv2,bv2,sm);
}

// ---------------- vel: bf16 = copy of fused result; f32 = old compute ----------------
template<bool F32>
__device__ void vel_body(const void* __restrict__ Wv1, const void* __restrict__ bv1,
                         const void* __restrict__ Wv2, const void* __restrict__ bv2,
                         void* __restrict__ out){
  const int b = blockIdx.x, t = threadIdx.x;
  if(F32){
    __shared__ float ql[NOBS];
    __shared__ float hl[HID];
    if(t<NOBS) ql[t] = g_q[(size_t)b*NOBS+t];
    __syncthreads();
    float acc = LD<F32>(bv1,t);
    #pragma unroll
    for(int k=0;k<NOBS;k++) acc += ql[k]*LD<F32>(Wv1,k*HID+t);
    hl[t] = silu(acc);
    __syncthreads();
    #pragma unroll
    for(int oo=0;oo<2;oo++){
      int o = t + oo*256;
      float s0=0.f;
      for(int k=0;k<HID;k++) s0 += hl[k]*LD<F32>(Wv2,(size_t)k*OUTDIM+o);
      ((float*)out)[(size_t)b*OUTDIM+o] = LD<F32>(bv2,o) + s0;
    }
  } else {
    ((unsigned*)out)[(size_t)b*(OUTDIM/2) + t] = g_out[(size_t)b*(OUTDIM/2) + t];
  }
}

__global__ __launch_bounds__(256) void k_vel(const void* Wv1,const void* bv1,
                                             const void* Wv2,const void* bv2, void* out){
  if(g_isf32) vel_body<true >(Wv1,bv1,Wv2,bv2,out);
  else        vel_body<false>(Wv1,bv1,Wv2,bv2,out);
}

extern "C" void kernel_launch(void* const* d_in, const int* in_sizes, int n_in,
                              void* d_out, int out_size, void* d_ws, size_t ws_size,
                              hipStream_t stream){
  const void* x    = d_in[0];
  const void* W1   = d_in[1];
  const void* b1   = d_in[2];
  const void* W2   = d_in[3];
  const void* b2   = d_in[4];
  const void* Aoff = d_in[5];
  const void* Boff = d_in[6];
  const void* Dd   = d_in[7];
  const void* Wv1  = d_in[8];
  const void* bv1  = d_in[9];
  const void* Wv2  = d_in[10];
  const void* bv2  = d_in[11];
  // d_in[12] (pauli) unused: H_eff built analytically from the Pauli-word structure.

  k_detect<<<1,256,0,stream>>>((const unsigned*)W1);
  k_enc  <<<1024,256,0,stream>>>(x,W1,b1,W2,b2);
  k_state<<<BATCH,256,0,stream>>>(Aoff,Boff,Dd,Wv1,bv1,Wv2,bv2);
  k_vel  <<<BATCH,256,0,stream>>>(Wv1,bv1,Wv2,bv2,d_out);
}